// Round 6
// baseline (1731.069 us; speedup 1.0000x reference)
//
#include <hip/hip_runtime.h>
#include <math.h>

#define SEQ   16384
#define DIM   1024
#define WU    32                    // warm-up steps (empirically proven r1/r2)
#define CHUNK 32
#define NCH   (SEQ / CHUNK)         // 512 chunks per direction
#define NSTR  (2 * NCH)             // 1024 parallel streams
#define NSTEP (WU + CHUNK)          // 64 batched steps

typedef __attribute__((ext_vector_type(8)))  short bf16x8;
typedef __attribute__((ext_vector_type(16))) float f32x16;

__device__ __forceinline__ unsigned short f2bf(float f) {
    unsigned int x = __float_as_uint(f);
    unsigned int r = (x + 0x7fffu + ((x >> 16) & 1u)) >> 16;
    return (unsigned short)r;
}
__device__ __forceinline__ float bf2f(unsigned short u) {
    return __uint_as_float(((unsigned int)u) << 16);
}

// ---------------------------------------------------------------------------
// W (KxN fp32) -> n-major NxK bf16 hi/lo pair (Wx and Wh).  (unchanged, r5)
// ---------------------------------------------------------------------------
__global__ __launch_bounds__(256)
void wsplit_kernel(const float* __restrict__ W,
                   unsigned short* __restrict__ WTh,
                   unsigned short* __restrict__ WTl)
{
    const int bk = blockIdx.x & 15, bn = blockIdx.x >> 4;
    const int k0 = bk * 64, n0 = bn * 64;
    const int tid = threadIdx.x;
    __shared__ float T[64][65];
#pragma unroll
    for (int it = 0; it < 4; ++it) {
        int f = tid + 256 * it;
        int r = f >> 4;
        int c4 = (f & 15) << 2;
        const float4 v = *reinterpret_cast<const float4*>(
            &W[(size_t)(k0 + r) * DIM + n0 + c4]);
        T[r][c4 + 0] = v.x; T[r][c4 + 1] = v.y;
        T[r][c4 + 2] = v.z; T[r][c4 + 3] = v.w;
    }
    __syncthreads();
#pragma unroll
    for (int it = 0; it < 4; ++it) {
        int f  = tid + 256 * it;
        int rn = f >> 4;
        int c4 = (f & 15) << 2;
        float vv[4] = {T[c4 + 0][rn], T[c4 + 1][rn], T[c4 + 2][rn], T[c4 + 3][rn]};
        ushort4 hi, lo;
        unsigned short h[4], l[4];
#pragma unroll
        for (int jj = 0; jj < 4; ++jj) {
            h[jj] = f2bf(vv[jj]);
            l[jj] = f2bf(vv[jj] - bf2f(h[jj]));
        }
        hi.x = h[0]; hi.y = h[1]; hi.z = h[2]; hi.w = h[3];
        lo.x = l[0]; lo.y = l[1]; lo.z = l[2]; lo.w = l[3];
        *reinterpret_cast<ushort4*>(&WTh[(size_t)(n0 + rn) * DIM + k0 + c4]) = hi;
        *reinterpret_cast<ushort4*>(&WTl[(size_t)(n0 + rn) * DIM + k0 + c4]) = lo;
    }
}

// ---------------------------------------------------------------------------
// x (fp32) -> xh/xl bf16 hi/lo. Memory-bound.  (unchanged, r5)
// ---------------------------------------------------------------------------
__global__ __launch_bounds__(256)
void xsplit_kernel(const float* __restrict__ x,
                   unsigned short* __restrict__ xh,
                   unsigned short* __restrict__ xl)
{
    const int N4 = SEQ * DIM / 4;
    for (int idx = blockIdx.x * 256 + threadIdx.x; idx < N4; idx += gridDim.x * 256) {
        const float4 v = reinterpret_cast<const float4*>(x)[idx];
        ushort4 h, l;
        h.x = f2bf(v.x); l.x = f2bf(v.x - bf2f(h.x));
        h.y = f2bf(v.y); l.y = f2bf(v.y - bf2f(h.y));
        h.z = f2bf(v.z); l.z = f2bf(v.z - bf2f(h.z));
        h.w = f2bf(v.w); l.w = f2bf(v.w - bf2f(h.w));
        reinterpret_cast<ushort4*>(xh)[idx] = h;
        reinterpret_cast<ushort4*>(xl)[idx] = l;
    }
}

// ---------------------------------------------------------------------------
// xproj = x @ Wx + b, MFMA 32x32x16, 3-term hi/lo (fp32-accurate). (r5)
// ---------------------------------------------------------------------------
__global__ __launch_bounds__(256)
void xproj_mfma(const unsigned short* __restrict__ xh,
                const unsigned short* __restrict__ xl,
                const unsigned short* __restrict__ WxTh,
                const unsigned short* __restrict__ WxTl,
                const float* __restrict__ b, float* __restrict__ xp)
{
    const int gb = (blockIdx.x & 7) * 256 + (blockIdx.x >> 3);
    const int bm = gb >> 4, bn = gb & 15;
    const int row0 = bm * 128, col0 = bn * 64;
    const int tid = threadIdx.x, lane = tid & 63, w = tid >> 6;
    const int wm = w >> 1, wn = w & 1;

    __shared__ unsigned short Ah[128][40], Al[128][40];
    __shared__ unsigned short Bh[64][40],  Bl[64][40];

    f32x16 acc[2];
#pragma unroll
    for (int mi = 0; mi < 2; ++mi)
#pragma unroll
        for (int r = 0; r < 16; ++r) acc[mi][r] = 0.f;

    const int ar = tid >> 1, ak = (tid & 1) * 16;
    const int br = tid >> 2, bk = (tid & 3) * 8;
    const size_t ga = (size_t)(row0 + ar) * DIM + ak;
    const size_t gbb = (size_t)(col0 + br) * DIM + bk;

    uint4 pah0, pah1, pal0, pal1, pbh, pbl;
#define XLOAD(k0_) do {                                                        \
        pah0 = *reinterpret_cast<const uint4*>(xh   + ga  + (k0_));            \
        pah1 = *reinterpret_cast<const uint4*>(xh   + ga  + (k0_) + 8);        \
        pal0 = *reinterpret_cast<const uint4*>(xl   + ga  + (k0_));            \
        pal1 = *reinterpret_cast<const uint4*>(xl   + ga  + (k0_) + 8);        \
        pbh  = *reinterpret_cast<const uint4*>(WxTh + gbb + (k0_));            \
        pbl  = *reinterpret_cast<const uint4*>(WxTl + gbb + (k0_));            \
    } while (0)

    XLOAD(0);
    const int am0 = wm * 64 + (lane & 31), am1 = am0 + 32;
    const int bn0 = wn * 32 + (lane & 31);
    const int kh  = (lane >> 5) * 8;

    for (int kt = 0; kt < 32; ++kt) {
        __syncthreads();
        *reinterpret_cast<uint4*>(&Ah[ar][ak])     = pah0;
        *reinterpret_cast<uint4*>(&Ah[ar][ak + 8]) = pah1;
        *reinterpret_cast<uint4*>(&Al[ar][ak])     = pal0;
        *reinterpret_cast<uint4*>(&Al[ar][ak + 8]) = pal1;
        *reinterpret_cast<uint4*>(&Bh[br][bk])     = pbh;
        *reinterpret_cast<uint4*>(&Bl[br][bk])     = pbl;
        __syncthreads();
        if (kt < 31) XLOAD((size_t)(kt + 1) * 32);
#pragma unroll
        for (int ks = 0; ks < 2; ++ks) {
            const int ko = ks * 16 + kh;
            bf16x8 a0h = *reinterpret_cast<const bf16x8*>(&Ah[am0][ko]);
            bf16x8 a1h = *reinterpret_cast<const bf16x8*>(&Ah[am1][ko]);
            bf16x8 a0l = *reinterpret_cast<const bf16x8*>(&Al[am0][ko]);
            bf16x8 a1l = *reinterpret_cast<const bf16x8*>(&Al[am1][ko]);
            bf16x8 bh  = *reinterpret_cast<const bf16x8*>(&Bh[bn0][ko]);
            bf16x8 bl  = *reinterpret_cast<const bf16x8*>(&Bl[bn0][ko]);
            acc[0] = __builtin_amdgcn_mfma_f32_32x32x16_bf16(a0h, bh, acc[0], 0, 0, 0);
            acc[1] = __builtin_amdgcn_mfma_f32_32x32x16_bf16(a1h, bh, acc[1], 0, 0, 0);
            acc[0] = __builtin_amdgcn_mfma_f32_32x32x16_bf16(a0h, bl, acc[0], 0, 0, 0);
            acc[1] = __builtin_amdgcn_mfma_f32_32x32x16_bf16(a1h, bl, acc[1], 0, 0, 0);
            acc[0] = __builtin_amdgcn_mfma_f32_32x32x16_bf16(a0l, bh, acc[0], 0, 0, 0);
            acc[1] = __builtin_amdgcn_mfma_f32_32x32x16_bf16(a1l, bh, acc[1], 0, 0, 0);
        }
    }
#undef XLOAD

    const int rbase = 4 * (lane >> 5);
    const int col = col0 + wn * 32 + (lane & 31);
    const float bb = b[col];
#pragma unroll
    for (int mi = 0; mi < 2; ++mi) {
#pragma unroll
        for (int r = 0; r < 16; ++r) {
            const int row = row0 + wm * 64 + mi * 32 + (r & 3) + 8 * (r >> 2) + rbase;
            xp[(size_t)row * DIM + col] = acc[mi][r] + bb;
        }
    }
}

// ---------------------------------------------------------------------------
// Persistent step kernel v3 — Wh in REGISTERS (immune to per-step L2 inv),
// single 129KB per-step A staging, k-quarter split + LDS reduce.
//   block: 64 streams x 64 cols; grid 256 = 16 slabs x 16 panels,
//   same-slab blocks grouped per XCD (slab = (b&7)*2 + ((b>>3)>>4)).
//   8 waves = 2 col-halves(nh) x 4 k-quarters(kq); wave = 64m x 32n x 256k,
//   mfma_32x32x16, B panel (32col x 256k hi+lo) = 128 VGPR/lane, loaded once.
//   A: LDS [64][1036] (stride 518dw === 6 mod 32 -> <=2-way conflicts).
//   Reduce buffer (48KB) aliases A. Barrier: r5's proven 2-level atomic.
// ---------------------------------------------------------------------------
__global__ __launch_bounds__(512, 2)
void step_persist3(unsigned short* __restrict__ Ha,
                   unsigned short* __restrict__ Hb,
                   const float* __restrict__ xp,
                   const unsigned short* __restrict__ WhTh,
                   const unsigned short* __restrict__ WhTl,
                   float* __restrict__ out,
                   unsigned int* bar)
{
    const int blk  = blockIdx.x;
    const int jj   = blk >> 3;
    const int slab = (blk & 7) * 2 + (jj >> 4);   // 0..15, co-XCD per slab pair
    const int panel = jj & 15;                    // 0..15
    const int row0 = slab * 64, col0 = panel * 64;
    const int grp  = blk & 15;
    const int tid = threadIdx.x, lane = tid & 63, w = tid >> 6;
    const int nh = w & 1, kq = w >> 1;

    __shared__ unsigned short A[64][1036];                 // 132.6 KB
    float* Red = reinterpret_cast<float*>(&A[0][0]);       // 48KB alias

    // ---- one-time: Wh panel fragment into registers (hi+lo, 128 VGPR) ----
    bf16x8 bh[16], bl[16];
    {
        const size_t bbase = (size_t)(col0 + nh * 32 + (lane & 31)) * DIM
                           + kq * 256 + (lane >> 5) * 8;
#pragma unroll
        for (int t = 0; t < 16; ++t) {
            bh[t] = *reinterpret_cast<const bf16x8*>(&WhTh[bbase + t * 16]);
            bl[t] = *reinterpret_cast<const bf16x8*>(&WhTl[bbase + t * 16]);
        }
    }

    const int strow = tid >> 3, stc = tid & 7;    // staging: 8 thr/row
    const size_t gH = (size_t)(row0 + strow) * DIM + stc * 8;
    const int am0 = lane & 31, am1 = 32 + (lane & 31);
    const int kfb = kq * 256 + (lane >> 5) * 8;
    const int col = col0 + nh * 32 + (lane & 31);

    for (int i = 0; i < NSTEP; ++i) {
        const unsigned short* Hin = (i & 1) ? Hb : Ha;
        unsigned short*      Hout = (i & 1) ? Ha : Hb;

        // ---- stage full H slab (64 x 1024) once, 8-deep pipelined ----
#pragma unroll
        for (int h2 = 0; h2 < 2; ++h2) {
            uint4 st[8];
#pragma unroll
            for (int q = 0; q < 8; ++q)
                st[q] = *reinterpret_cast<const uint4*>(
                    Hin + gH + (size_t)(h2 * 8 + q) * 64);
#pragma unroll
            for (int q = 0; q < 8; ++q)
                *reinterpret_cast<uint4*>(
                    &A[strow][(stc + 8 * (h2 * 8 + q)) * 8]) = st[q];
        }

        // ---- xp prefetch (kq==0 waves only; wave-uniform branch) ----
        float xpv[2][16];
        if (kq == 0) {
#pragma unroll
            for (int f = 0; f < 2; ++f)
#pragma unroll
                for (int r = 0; r < 16; ++r) {
                    const int srow = (r & 3) + 8 * (r >> 2) + 4 * (lane >> 5);
                    const int s = row0 + f * 32 + srow;
                    const int t = (s & 511) * CHUNK + (i - WU);
                    const int xrow = (t < 0) ? 0 : ((s >> 9) ? (SEQ - 1 - t) : t);
                    xpv[f][r] = xp[(size_t)xrow * DIM + col];
                }
        }
        __syncthreads();                          // staging visible

        // ---- MFMA over this wave's k-quarter, B from registers ----
        f32x16 acc0, acc1;
#pragma unroll
        for (int r = 0; r < 16; ++r) { acc0[r] = 0.f; acc1[r] = 0.f; }
#pragma unroll
        for (int t = 0; t < 16; ++t) {
            const bf16x8 a0 = *reinterpret_cast<const bf16x8*>(&A[am0][kfb + t * 16]);
            const bf16x8 a1 = *reinterpret_cast<const bf16x8*>(&A[am1][kfb + t * 16]);
            acc0 = __builtin_amdgcn_mfma_f32_32x32x16_bf16(a0, bh[t], acc0, 0, 0, 0);
            acc1 = __builtin_amdgcn_mfma_f32_32x32x16_bf16(a1, bh[t], acc1, 0, 0, 0);
            acc0 = __builtin_amdgcn_mfma_f32_32x32x16_bf16(a0, bl[t], acc0, 0, 0, 0);
            acc1 = __builtin_amdgcn_mfma_f32_32x32x16_bf16(a1, bl[t], acc1, 0, 0, 0);
        }
        __syncthreads();                          // A reads done -> Red alias safe

        // ---- k-quarter reduce: kq 1..3 write partials ----
        if (kq > 0) {
            const int base = ((nh * 3 + (kq - 1)) * 2) * 16 * 64;
#pragma unroll
            for (int r = 0; r < 16; ++r) {
                Red[base + r * 64 + lane]        = acc0[r];
                Red[base + (16 + r) * 64 + lane] = acc1[r];
            }
        }
        __syncthreads();

        // ---- kq==0: combine + tanh + stores ----
        if (kq == 0) {
#pragma unroll
            for (int f = 0; f < 2; ++f) {
#pragma unroll
                for (int r = 0; r < 16; ++r) {
                    float v = f ? acc1[r] : acc0[r];
#pragma unroll
                    for (int q = 0; q < 3; ++q)
                        v += Red[(((nh * 3 + q) * 2 + f) * 16 + r) * 64 + lane];
                    const int srow = (r & 3) + 8 * (r >> 2) + 4 * (lane >> 5);
                    const int s = row0 + f * 32 + srow;
                    const int t = (s & 511) * CHUNK + (i - WU);
                    float h = 0.f;
                    if (t >= 0) h = tanhf(v + xpv[f][r]);
                    Hout[(size_t)s * DIM + col] = f2bf(h);
                    if (i >= WU) {
                        const int orow = (s >> 9) ? (SEQ + t) : t;
                        out[(size_t)orow * DIM + col] = h;
                    }
                }
            }
        }

        // ---- device barrier (r5's proven 2-level release/acquire) ----
        if (i < NSTEP - 1) {
            asm volatile("s_waitcnt vmcnt(0)" ::: "memory");
            __syncthreads();
            if (tid == 0) {
                __threadfence();   // release: wb L2 (H -> L3)
                __hip_atomic_fetch_add(&bar[grp * 16], 1u,
                                       __ATOMIC_RELAXED, __HIP_MEMORY_SCOPE_AGENT);
                if (blockIdx.x < 16) {   // group master
                    while (__hip_atomic_load(&bar[grp * 16], __ATOMIC_RELAXED,
                                             __HIP_MEMORY_SCOPE_AGENT) < 16u * (i + 1))
                        __builtin_amdgcn_s_sleep(1);
                    __hip_atomic_fetch_add(&bar[256], 1u,
                                           __ATOMIC_RELAXED, __HIP_MEMORY_SCOPE_AGENT);
                }
                while (__hip_atomic_load(&bar[256], __ATOMIC_RELAXED,
                                         __HIP_MEMORY_SCOPE_AGENT) < 16u * (i + 1))
                    __builtin_amdgcn_s_sleep(1);
                __threadfence();   // acquire: inv (Wh safe in VGPRs)
            }
            __syncthreads();
        }
    }
}

// ---------------------------------------------------------------------------
extern "C" void kernel_launch(void* const* d_in, const int* in_sizes, int n_in,
                              void* d_out, int out_size, void* d_ws, size_t ws_size,
                              hipStream_t stream)
{
    (void)in_sizes; (void)n_in; (void)out_size; (void)ws_size;
    const float* x  = (const float*)d_in[0];
    const float* Wx = (const float*)d_in[1];
    const float* Wh = (const float*)d_in[2];
    const float* b  = (const float*)d_in[3];
    float* out = (float*)d_out;

    char* ws = (char*)d_ws;
    const size_t MB = 1ull << 20;
    float*          xp   = (float*)ws;                        // [0, 64MB)
    unsigned short* WxTh = (unsigned short*)(ws + 64 * MB);
    unsigned short* WxTl = (unsigned short*)(ws + 66 * MB);
    unsigned short* WhTh = (unsigned short*)(ws + 68 * MB);
    unsigned short* WhTl = (unsigned short*)(ws + 70 * MB);
    unsigned short* H0   = (unsigned short*)(ws + 72 * MB);
    unsigned short* H1   = (unsigned short*)(ws + 74 * MB);
    unsigned int*   bar  = (unsigned int*)(ws + 76 * MB);     // 2KB counters

    unsigned short* xh = (unsigned short*)d_out;   // first 64MB of out, freed
    unsigned short* xl = xh + (size_t)SEQ * DIM;   // before steps write out

    hipLaunchKernelGGL(wsplit_kernel, dim3(256), dim3(256), 0, stream, Wx, WxTh, WxTl);
    hipLaunchKernelGGL(wsplit_kernel, dim3(256), dim3(256), 0, stream, Wh, WhTh, WhTl);
    hipLaunchKernelGGL(xsplit_kernel, dim3(2048), dim3(256), 0, stream, x, xh, xl);
    hipLaunchKernelGGL(xproj_mfma, dim3(2048), dim3(256), 0, stream,
                       xh, xl, WxTh, WxTl, b, xp);
    hipMemsetAsync(H0, 0, 2 * MB, stream);
    hipMemsetAsync(bar, 0, 2048, stream);

    void* args[] = {(void*)&H0, (void*)&H1, (void*)&xp,
                    (void*)&WhTh, (void*)&WhTl, (void*)&out, (void*)&bar};
    hipLaunchCooperativeKernel((void*)step_persist3, dim3(256), dim3(512),
                               args, 0, stream);
}

// Round 8
// 1024.806 us; speedup vs baseline: 1.6892x; 1.6892x over previous
//
#include <hip/hip_runtime.h>
#include <math.h>

#define SEQ   16384
#define DIM   1024
#define WU    32                    // warm-up steps (empirically proven r1/r2)
#define CHUNK 32
#define NCH   (SEQ / CHUNK)         // 512 chunks per direction
#define NSTR  (2 * NCH)             // 1024 parallel streams
#define NSTEP (WU + CHUNK)          // 64 batched steps

typedef _Float16 half_t;
typedef __attribute__((ext_vector_type(4)))  _Float16 f16x4;
typedef __attribute__((ext_vector_type(8)))  _Float16 f16x8;
typedef __attribute__((ext_vector_type(16))) float    f32x16;

// coherence-point (sc0 sc1) access helpers for cross-block H exchange.
__device__ __forceinline__ uint4 ld_coh16(const void* p) {
    uint4 r;
    asm volatile("global_load_dwordx4 %0, %1, off sc0 sc1" : "=v"(r) : "v"(p));
    return r;
}
__device__ __forceinline__ void st_coh2(void* p, unsigned short v) {
    asm volatile("global_store_short %0, %1, off sc0 sc1"
                 :: "v"(p), "v"((unsigned int)v) : "memory");
}

// ---------------------------------------------------------------------------
// W (KxN fp32) -> n-major NxK fp16.  Used for Wx and Wh.
// ---------------------------------------------------------------------------
__global__ __launch_bounds__(256)
void whalf_kernel(const float* __restrict__ W, half_t* __restrict__ WT)
{
    const int bk = blockIdx.x & 15, bn = blockIdx.x >> 4;
    const int k0 = bk * 64, n0 = bn * 64;
    const int tid = threadIdx.x;
    __shared__ float T[64][65];
#pragma unroll
    for (int it = 0; it < 4; ++it) {
        int f = tid + 256 * it;
        int r = f >> 4;
        int c4 = (f & 15) << 2;
        const float4 v = *reinterpret_cast<const float4*>(
            &W[(size_t)(k0 + r) * DIM + n0 + c4]);
        T[r][c4 + 0] = v.x; T[r][c4 + 1] = v.y;
        T[r][c4 + 2] = v.z; T[r][c4 + 3] = v.w;
    }
    __syncthreads();
#pragma unroll
    for (int it = 0; it < 4; ++it) {
        int f  = tid + 256 * it;
        int rn = f >> 4;
        int c4 = (f & 15) << 2;
        f16x4 o;
        o[0] = (half_t)T[c4 + 0][rn]; o[1] = (half_t)T[c4 + 1][rn];
        o[2] = (half_t)T[c4 + 2][rn]; o[3] = (half_t)T[c4 + 3][rn];
        *reinterpret_cast<f16x4*>(&WT[(size_t)(n0 + rn) * DIM + k0 + c4]) = o;
    }
}

// ---------------------------------------------------------------------------
// x (fp32) -> fp16, same layout. Memory-bound.
// ---------------------------------------------------------------------------
__global__ __launch_bounds__(256)
void xhalf_kernel(const float* __restrict__ x, half_t* __restrict__ xh)
{
    const int N8 = SEQ * DIM / 8;
    for (int idx = blockIdx.x * 256 + threadIdx.x; idx < N8; idx += gridDim.x * 256) {
        const float4 a = reinterpret_cast<const float4*>(x)[2 * idx];
        const float4 b = reinterpret_cast<const float4*>(x)[2 * idx + 1];
        f16x8 o;
        o[0] = (half_t)a.x; o[1] = (half_t)a.y; o[2] = (half_t)a.z; o[3] = (half_t)a.w;
        o[4] = (half_t)b.x; o[5] = (half_t)b.y; o[6] = (half_t)b.z; o[7] = (half_t)b.w;
        reinterpret_cast<f16x8*>(xh)[idx] = o;
    }
}

// ---------------------------------------------------------------------------
// xproj = x @ Wx + b, MFMA 32x32x16 fp16 single-term.
// r8 FIX: A staging covers all 128 rows (r7 bug: ar=tid>>2 staged only rows
// 0..63; Ah[64..127] was uninitialized LDS -> NaN). Now ar=tid>>1 with two
// uint4 loads/thread, identical coverage to the proven r4-r6 bf16 version.
// ---------------------------------------------------------------------------
__global__ __launch_bounds__(256)
void xproj_f16(const half_t* __restrict__ xh, const half_t* __restrict__ WxT,
               const float* __restrict__ b, float* __restrict__ xp)
{
    const int gb = (blockIdx.x & 7) * 256 + (blockIdx.x >> 3);
    const int bm = gb >> 4, bn = gb & 15;
    const int row0 = bm * 128, col0 = bn * 64;
    const int tid = threadIdx.x, lane = tid & 63, w = tid >> 6;
    const int wm = w >> 1, wn = w & 1;

    __shared__ half_t Ah[128][40], Bh[64][40];

    f32x16 acc[2];
#pragma unroll
    for (int mi = 0; mi < 2; ++mi)
#pragma unroll
        for (int r = 0; r < 16; ++r) acc[mi][r] = 0.f;

    const int ar = tid >> 1, ak = (tid & 1) * 16;   // A: 128r x 32k, 2 uint4/thr
    const int br = tid >> 2, bk2 = (tid & 3) * 8;   // B: 64r x 32k, 1 uint4/thr
    const size_t ga  = (size_t)(row0 + ar) * DIM + ak;
    const size_t gbb = (size_t)(col0 + br) * DIM + bk2;

    uint4 pa0, pa1, pb;
#define XLOAD(k0_) do {                                                        \
        pa0 = *reinterpret_cast<const uint4*>(xh + ga + (k0_));                \
        pa1 = *reinterpret_cast<const uint4*>(xh + ga + (k0_) + 8);            \
        pb  = *reinterpret_cast<const uint4*>(WxT + gbb + (k0_));              \
    } while (0)

    XLOAD(0);
    const int am0 = wm * 64 + (lane & 31), am1 = am0 + 32;
    const int bn0 = wn * 32 + (lane & 31);
    const int kh  = (lane >> 5) * 8;

    for (int kt = 0; kt < 32; ++kt) {
        __syncthreads();
        *reinterpret_cast<uint4*>(&Ah[ar][ak])     = pa0;
        *reinterpret_cast<uint4*>(&Ah[ar][ak + 8]) = pa1;
        *reinterpret_cast<uint4*>(&Bh[br][bk2])    = pb;
        __syncthreads();
        if (kt < 31) XLOAD((size_t)(kt + 1) * 32);
#pragma unroll
        for (int ks = 0; ks < 2; ++ks) {
            const int ko = ks * 16 + kh;
            f16x8 a0 = *reinterpret_cast<const f16x8*>(&Ah[am0][ko]);
            f16x8 a1 = *reinterpret_cast<const f16x8*>(&Ah[am1][ko]);
            f16x8 bb = *reinterpret_cast<const f16x8*>(&Bh[bn0][ko]);
            acc[0] = __builtin_amdgcn_mfma_f32_32x32x16_f16(a0, bb, acc[0], 0, 0, 0);
            acc[1] = __builtin_amdgcn_mfma_f32_32x32x16_f16(a1, bb, acc[1], 0, 0, 0);
        }
    }
#undef XLOAD

    // C layout (m74/m101): col = lane&31, row = (r&3) + 8*(r>>2) + 4*(lane>>5)
    const int rbase = 4 * (lane >> 5);
    const int col = col0 + wn * 32 + (lane & 31);
    const float bb = b[col];
#pragma unroll
    for (int mi = 0; mi < 2; ++mi) {
#pragma unroll
        for (int r = 0; r < 16; ++r) {
            const int row = row0 + wm * 64 + mi * 32 + (r & 3) + 8 * (r >> 2) + rbase;
            xp[(size_t)row * DIM + col] = acc[mi][r] + bb;
        }
    }
}

// ---------------------------------------------------------------------------
// Persistent step kernel v4 (unchanged from r7 — evaluating slab barrier).
//   * fp16 single-term: S = H_f16 * Wh_f16
//   * B (Wh panel) in regs: 64 VGPR/lane
//   * SLAB-LOCAL barrier: only the 16 blocks of a slab sync; relaxed
//     device-scope atomics, NO threadfence -> no per-step L2 invalidate.
//     H exchanged via sc0/sc1 coherent ops.
//   * A slab staged to LDS once/step (r6 layout: 0 bank conflicts measured).
// Block: 64 streams x 64 cols; grid 256 = 16 slabs x 16 panels.
// 8 waves = 2 col-halves(nh) x 4 k-quarters(kq); reduce via LDS alias.
// ---------------------------------------------------------------------------
__global__ __launch_bounds__(512)
void step_persist4(half_t* __restrict__ Ha,
                   half_t* __restrict__ Hb,
                   const float* __restrict__ xp,
                   const half_t* __restrict__ WhT,
                   float* __restrict__ out,
                   unsigned int* bar)
{
    const int slab = blockIdx.x >> 4;             // 0..15
    const int panel = blockIdx.x & 15;            // 0..15
    const int row0 = slab * 64, col0 = panel * 64;
    const int tid = threadIdx.x, lane = tid & 63, w = tid >> 6;
    const int nh = w & 1, kq = w >> 1;

    __shared__ half_t A[64][1036];                         // 129.5 KB
    float* Red = reinterpret_cast<float*>(&A[0][0]);       // 48KB alias

    // ---- one-time: Wh panel fragment into registers (64 VGPR) ----
    f16x8 bh[16];
    {
        const size_t bbase = (size_t)(col0 + nh * 32 + (lane & 31)) * DIM
                           + kq * 256 + (lane >> 5) * 8;
#pragma unroll
        for (int t = 0; t < 16; ++t)
            bh[t] = *reinterpret_cast<const f16x8*>(&WhT[bbase + t * 16]);
    }

    const int strow = tid >> 3, stc = tid & 7;    // staging: 8 thr/row
    const size_t gH = (size_t)(row0 + strow) * DIM + stc * 8;
    const int am0 = lane & 31, am1 = 32 + (lane & 31);
    const int kfb = kq * 256 + (lane >> 5) * 8;
    const int col = col0 + nh * 32 + (lane & 31);
    unsigned int* mybar = bar + slab * 32;        // 128B-isolated counter

    for (int i = 0; i < NSTEP; ++i) {
        const half_t* Hin = (i & 1) ? Hb : Ha;
        half_t*      Hout = (i & 1) ? Ha : Hb;

        // ---- xp prefetch (kq==0 waves; cached loads, overlap with stage) ----
        float xpv[2][16];
        if (kq == 0) {
#pragma unroll
            for (int f = 0; f < 2; ++f)
#pragma unroll
                for (int r = 0; r < 16; ++r) {
                    const int srow = (r & 3) + 8 * (r >> 2) + 4 * (lane >> 5);
                    const int s = row0 + f * 32 + srow;
                    const int t = (s & 511) * CHUNK + (i - WU);
                    const int xrow = (t < 0) ? 0 : ((s >> 9) ? (SEQ - 1 - t) : t);
                    xpv[f][r] = xp[(size_t)xrow * DIM + col];
                }
        }

        // ---- stage H slab (64 x 1024 fp16) via coherent loads ----
        uint4 st[16];
#pragma unroll
        for (int q = 0; q < 16; ++q)
            st[q] = ld_coh16(Hin + gH + (size_t)q * 64);
        asm volatile("s_waitcnt vmcnt(0)" ::: "memory");
        __builtin_amdgcn_sched_barrier(0);
#pragma unroll
        for (int q = 0; q < 16; ++q)
            *reinterpret_cast<uint4*>(&A[strow][(stc + 8 * q) * 8]) = st[q];
        __syncthreads();

        // ---- MFMA over this wave's k-quarter, B from registers ----
        f32x16 acc0, acc1;
#pragma unroll
        for (int r = 0; r < 16; ++r) { acc0[r] = 0.f; acc1[r] = 0.f; }
#pragma unroll
        for (int t = 0; t < 16; ++t) {
            const f16x8 a0 = *reinterpret_cast<const f16x8*>(&A[am0][kfb + t * 16]);
            const f16x8 a1 = *reinterpret_cast<const f16x8*>(&A[am1][kfb + t * 16]);
            acc0 = __builtin_amdgcn_mfma_f32_32x32x16_f16(a0, bh[t], acc0, 0, 0, 0);
            acc1 = __builtin_amdgcn_mfma_f32_32x32x16_f16(a1, bh[t], acc1, 0, 0, 0);
        }
        __syncthreads();                          // A reads done -> Red alias safe

        // ---- k-quarter reduce: kq 1..3 write partials ----
        if (kq > 0) {
            const int base = ((nh * 3 + (kq - 1)) * 2) * 16 * 64;
#pragma unroll
            for (int r = 0; r < 16; ++r) {
                Red[base + r * 64 + lane]        = acc0[r];
                Red[base + (16 + r) * 64 + lane] = acc1[r];
            }
        }
        __syncthreads();

        // ---- kq==0: combine + tanh + coherent H store + out store ----
        if (kq == 0) {
#pragma unroll
            for (int f = 0; f < 2; ++f) {
#pragma unroll
                for (int r = 0; r < 16; ++r) {
                    float v = f ? acc1[r] : acc0[r];
#pragma unroll
                    for (int q = 0; q < 3; ++q)
                        v += Red[(((nh * 3 + q) * 2 + f) * 16 + r) * 64 + lane];
                    const int srow = (r & 3) + 8 * (r >> 2) + 4 * (lane >> 5);
                    const int s = row0 + f * 32 + srow;
                    const int t = (s & 511) * CHUNK + (i - WU);
                    float h = 0.f;
                    if (t >= 0) h = tanhf(v + xpv[f][r]);
                    const half_t hh = (half_t)h;
                    st_coh2(Hout + (size_t)s * DIM + col,
                            *reinterpret_cast<const unsigned short*>(&hh));
                    if (i >= WU) {
                        const int orow = (s >> 9) ? (SEQ + t) : t;
                        out[(size_t)orow * DIM + col] = h;
                    }
                }
            }
        }

        // ---- slab-local barrier: 16 blocks, relaxed atomics, no fences ----
        if (i < NSTEP - 1) {
            asm volatile("s_waitcnt vmcnt(0)" ::: "memory");   // H stores done
            __syncthreads();
            if (tid == 0) {
                __hip_atomic_fetch_add(mybar, 1u,
                                       __ATOMIC_RELAXED, __HIP_MEMORY_SCOPE_AGENT);
                while (__hip_atomic_load(mybar, __ATOMIC_RELAXED,
                                         __HIP_MEMORY_SCOPE_AGENT) < 16u * (i + 1))
                    __builtin_amdgcn_s_sleep(1);
            }
            __syncthreads();
        }
    }
}

// ---------------------------------------------------------------------------
extern "C" void kernel_launch(void* const* d_in, const int* in_sizes, int n_in,
                              void* d_out, int out_size, void* d_ws, size_t ws_size,
                              hipStream_t stream)
{
    (void)in_sizes; (void)n_in; (void)out_size; (void)ws_size;
    const float* x  = (const float*)d_in[0];
    const float* Wx = (const float*)d_in[1];
    const float* Wh = (const float*)d_in[2];
    const float* b  = (const float*)d_in[3];
    float* out = (float*)d_out;

    char* ws = (char*)d_ws;
    const size_t MB = 1ull << 20;
    float*  xp  = (float*)ws;                        // [0, 64MB)
    half_t* WxT = (half_t*)(ws + 64 * MB);           // 2MB
    half_t* WhT = (half_t*)(ws + 66 * MB);           // 2MB
    half_t* H0  = (half_t*)(ws + 68 * MB);           // 2MB
    half_t* H1  = (half_t*)(ws + 70 * MB);           // 2MB
    unsigned int* bar = (unsigned int*)(ws + 72 * MB);  // 2KB counters

    half_t* xh = (half_t*)d_out;    // first 32MB of out; consumed by xproj
                                    // before steps overwrite out (stream order)

    hipLaunchKernelGGL(whalf_kernel, dim3(256), dim3(256), 0, stream, Wx, WxT);
    hipLaunchKernelGGL(whalf_kernel, dim3(256), dim3(256), 0, stream, Wh, WhT);
    hipLaunchKernelGGL(xhalf_kernel, dim3(1024), dim3(256), 0, stream, x, xh);
    hipLaunchKernelGGL(xproj_f16, dim3(2048), dim3(256), 0, stream,
                       xh, WxT, b, xp);
    hipMemsetAsync(H0, 0, 2 * MB, stream);
    hipMemsetAsync(bar, 0, 2048, stream);

    void* args[] = {(void*)&H0, (void*)&H1, (void*)&xp,
                    (void*)&WhT, (void*)&out, (void*)&bar};
    hipLaunchCooperativeKernel((void*)step_persist4, dim3(256), dim3(512),
                               args, 0, stream);
}

// Round 9
// 723.716 us; speedup vs baseline: 2.3919x; 1.4160x over previous
//
#include <hip/hip_runtime.h>
#include <math.h>

#define SEQ   16384
#define DIM   1024
#define WU    32                    // warm-up steps (empirically proven r1/r2)
#define CHUNK 32
#define NCH   (SEQ / CHUNK)         // 512 chunks per direction
#define NSTR  (2 * NCH)             // 1024 parallel streams
#define NSTEP (WU + CHUNK)          // 64 batched steps

typedef _Float16 half_t;
typedef __attribute__((ext_vector_type(4)))  _Float16 f16x4;
typedef __attribute__((ext_vector_type(8)))  _Float16 f16x8;
typedef __attribute__((ext_vector_type(16))) float    f32x16;

// Intra-XCD coherent access: sc0 bypasses L1 (stale-line hazard) but is
// served by the XCD-shared L2. Slab blocks are co-XCD by construction.
__device__ __forceinline__ uint4 ld_l2(const void* p) {
    uint4 r;
    asm volatile("global_load_dwordx4 %0, %1, off sc0" : "=v"(r) : "v"(p));
    return r;
}
__device__ __forceinline__ void st_l2(void* p, unsigned short v) {
    asm volatile("global_store_short %0, %1, off sc0"
                 :: "v"(p), "v"((unsigned int)v) : "memory");
}

// ---------------------------------------------------------------------------
// W (KxN fp32) -> n-major NxK fp16.  Used for Wx and Wh.
// ---------------------------------------------------------------------------
__global__ __launch_bounds__(256)
void whalf_kernel(const float* __restrict__ W, half_t* __restrict__ WT)
{
    const int bk = blockIdx.x & 15, bn = blockIdx.x >> 4;
    const int k0 = bk * 64, n0 = bn * 64;
    const int tid = threadIdx.x;
    __shared__ float T[64][65];
#pragma unroll
    for (int it = 0; it < 4; ++it) {
        int f = tid + 256 * it;
        int r = f >> 4;
        int c4 = (f & 15) << 2;
        const float4 v = *reinterpret_cast<const float4*>(
            &W[(size_t)(k0 + r) * DIM + n0 + c4]);
        T[r][c4 + 0] = v.x; T[r][c4 + 1] = v.y;
        T[r][c4 + 2] = v.z; T[r][c4 + 3] = v.w;
    }
    __syncthreads();
#pragma unroll
    for (int it = 0; it < 4; ++it) {
        int f  = tid + 256 * it;
        int rn = f >> 4;
        int c4 = (f & 15) << 2;
        f16x4 o;
        o[0] = (half_t)T[c4 + 0][rn]; o[1] = (half_t)T[c4 + 1][rn];
        o[2] = (half_t)T[c4 + 2][rn]; o[3] = (half_t)T[c4 + 3][rn];
        *reinterpret_cast<f16x4*>(&WT[(size_t)(n0 + rn) * DIM + k0 + c4]) = o;
    }
}

// ---------------------------------------------------------------------------
// x (fp32) -> fp16, same layout. Memory-bound.
// ---------------------------------------------------------------------------
__global__ __launch_bounds__(256)
void xhalf_kernel(const float* __restrict__ x, half_t* __restrict__ xh)
{
    const int N8 = SEQ * DIM / 8;
    for (int idx = blockIdx.x * 256 + threadIdx.x; idx < N8; idx += gridDim.x * 256) {
        const float4 a = reinterpret_cast<const float4*>(x)[2 * idx];
        const float4 b = reinterpret_cast<const float4*>(x)[2 * idx + 1];
        f16x8 o;
        o[0] = (half_t)a.x; o[1] = (half_t)a.y; o[2] = (half_t)a.z; o[3] = (half_t)a.w;
        o[4] = (half_t)b.x; o[5] = (half_t)b.y; o[6] = (half_t)b.z; o[7] = (half_t)b.w;
        reinterpret_cast<f16x8*>(xh)[idx] = o;
    }
}

// ---------------------------------------------------------------------------
// xproj = x @ Wx + b, MFMA 32x32x16 fp16 single-term. (r8 version, proven)
// ---------------------------------------------------------------------------
__global__ __launch_bounds__(256)
void xproj_f16(const half_t* __restrict__ xh, const half_t* __restrict__ WxT,
               const float* __restrict__ b, float* __restrict__ xp)
{
    const int gb = (blockIdx.x & 7) * 256 + (blockIdx.x >> 3);
    const int bm = gb >> 4, bn = gb & 15;
    const int row0 = bm * 128, col0 = bn * 64;
    const int tid = threadIdx.x, lane = tid & 63, w = tid >> 6;
    const int wm = w >> 1, wn = w & 1;

    __shared__ half_t Ah[128][40], Bh[64][40];

    f32x16 acc[2];
#pragma unroll
    for (int mi = 0; mi < 2; ++mi)
#pragma unroll
        for (int r = 0; r < 16; ++r) acc[mi][r] = 0.f;

    const int ar = tid >> 1, ak = (tid & 1) * 16;   // A: 128r x 32k, 2 uint4/thr
    const int br = tid >> 2, bk2 = (tid & 3) * 8;   // B: 64r x 32k, 1 uint4/thr
    const size_t ga  = (size_t)(row0 + ar) * DIM + ak;
    const size_t gbb = (size_t)(col0 + br) * DIM + bk2;

    uint4 pa0, pa1, pb;
#define XLOAD(k0_) do {                                                        \
        pa0 = *reinterpret_cast<const uint4*>(xh + ga + (k0_));                \
        pa1 = *reinterpret_cast<const uint4*>(xh + ga + (k0_) + 8);            \
        pb  = *reinterpret_cast<const uint4*>(WxT + gbb + (k0_));              \
    } while (0)

    XLOAD(0);
    const int am0 = wm * 64 + (lane & 31), am1 = am0 + 32;
    const int bn0 = wn * 32 + (lane & 31);
    const int kh  = (lane >> 5) * 8;

    for (int kt = 0; kt < 32; ++kt) {
        __syncthreads();
        *reinterpret_cast<uint4*>(&Ah[ar][ak])     = pa0;
        *reinterpret_cast<uint4*>(&Ah[ar][ak + 8]) = pa1;
        *reinterpret_cast<uint4*>(&Bh[br][bk2])    = pb;
        __syncthreads();
        if (kt < 31) XLOAD((size_t)(kt + 1) * 32);
#pragma unroll
        for (int ks = 0; ks < 2; ++ks) {
            const int ko = ks * 16 + kh;
            f16x8 a0 = *reinterpret_cast<const f16x8*>(&Ah[am0][ko]);
            f16x8 a1 = *reinterpret_cast<const f16x8*>(&Ah[am1][ko]);
            f16x8 bb = *reinterpret_cast<const f16x8*>(&Bh[bn0][ko]);
            acc[0] = __builtin_amdgcn_mfma_f32_32x32x16_f16(a0, bb, acc[0], 0, 0, 0);
            acc[1] = __builtin_amdgcn_mfma_f32_32x32x16_f16(a1, bb, acc[1], 0, 0, 0);
        }
    }
#undef XLOAD

    // C layout (m74/m101): col = lane&31, row = (r&3) + 8*(r>>2) + 4*(lane>>5)
    const int rbase = 4 * (lane >> 5);
    const int col = col0 + wn * 32 + (lane & 31);
    const float bb = b[col];
#pragma unroll
    for (int mi = 0; mi < 2; ++mi) {
#pragma unroll
        for (int r = 0; r < 16; ++r) {
            const int row = row0 + wm * 64 + mi * 32 + (r & 3) + 8 * (r >> 2) + rbase;
            xp[(size_t)row * DIM + col] = acc[mi][r] + bb;
        }
    }
}

// ---------------------------------------------------------------------------
// Persistent step kernel v5 = r8's v4 with intra-XCD H exchange:
//   * slab blocks co-located on one XCD: slab=(blk&7)*2+((blk>>3)&1),
//     panel=blk>>4  -> all 16 blocks of a slab have blk%8 == slab>>1
//     (cooperative dispatch round-robins XCDs, m09).
//   * H loads/stores sc0-only (L1 bypass, served by XCD-shared L2):
//     the 32MB/step device-coherent read amplification of r8 (FETCH 663MB,
//     fetch-bound at 730GB/s) becomes intra-XCD L2 traffic.
//   * staging split 8+8 (r8's 16 live uint4 oversubscribed VGPRs).
// Everything else byte-identical to r8 (absmax 0.0039 proven).
// ---------------------------------------------------------------------------
__global__ __launch_bounds__(512)
void step_persist5(half_t* __restrict__ Ha,
                   half_t* __restrict__ Hb,
                   const float* __restrict__ xp,
                   const half_t* __restrict__ WhT,
                   float* __restrict__ out,
                   unsigned int* bar)
{
    const int blk = blockIdx.x;
    const int slab = (blk & 7) * 2 + ((blk >> 3) & 1);   // co-XCD per slab
    const int panel = blk >> 4;                          // 0..15
    const int row0 = slab * 64, col0 = panel * 64;
    const int tid = threadIdx.x, lane = tid & 63, w = tid >> 6;
    const int nh = w & 1, kq = w >> 1;

    __shared__ half_t A[64][1036];                         // 129.5 KB
    float* Red = reinterpret_cast<float*>(&A[0][0]);       // 48KB alias

    // ---- one-time: Wh panel fragment into registers (64 VGPR) ----
    f16x8 bh[16];
    {
        const size_t bbase = (size_t)(col0 + nh * 32 + (lane & 31)) * DIM
                           + kq * 256 + (lane >> 5) * 8;
#pragma unroll
        for (int t = 0; t < 16; ++t)
            bh[t] = *reinterpret_cast<const f16x8*>(&WhT[bbase + t * 16]);
    }

    const int strow = tid >> 3, stc = tid & 7;    // staging: 8 thr/row
    const size_t gH = (size_t)(row0 + strow) * DIM + stc * 8;
    const int am0 = lane & 31, am1 = 32 + (lane & 31);
    const int kfb = kq * 256 + (lane >> 5) * 8;
    const int col = col0 + nh * 32 + (lane & 31);
    unsigned int* mybar = bar + slab * 32;        // 128B-isolated counter

    for (int i = 0; i < NSTEP; ++i) {
        const half_t* Hin = (i & 1) ? Hb : Ha;
        half_t*      Hout = (i & 1) ? Ha : Hb;

        // ---- xp prefetch (kq==0 waves; overlap with stage) ----
        float xpv[2][16];
        if (kq == 0) {
#pragma unroll
            for (int f = 0; f < 2; ++f)
#pragma unroll
                for (int r = 0; r < 16; ++r) {
                    const int srow = (r & 3) + 8 * (r >> 2) + 4 * (lane >> 5);
                    const int s = row0 + f * 32 + srow;
                    const int t = (s & 511) * CHUNK + (i - WU);
                    const int xrow = (t < 0) ? 0 : ((s >> 9) ? (SEQ - 1 - t) : t);
                    xpv[f][r] = xp[(size_t)xrow * DIM + col];
                }
        }

        // ---- stage H slab (64 x 1024 fp16) from XCD L2, 2 batches of 8 ----
#pragma unroll
        for (int hb2 = 0; hb2 < 2; ++hb2) {
            uint4 st[8];
#pragma unroll
            for (int q = 0; q < 8; ++q)
                st[q] = ld_l2(Hin + gH + (size_t)(hb2 * 8 + q) * 64);
            asm volatile("s_waitcnt vmcnt(0)" ::: "memory");
            __builtin_amdgcn_sched_barrier(0);
#pragma unroll
            for (int q = 0; q < 8; ++q)
                *reinterpret_cast<uint4*>(
                    &A[strow][(stc + 8 * (hb2 * 8 + q)) * 8]) = st[q];
        }
        __syncthreads();

        // ---- MFMA over this wave's k-quarter, B from registers ----
        f32x16 acc0, acc1;
#pragma unroll
        for (int r = 0; r < 16; ++r) { acc0[r] = 0.f; acc1[r] = 0.f; }
#pragma unroll
        for (int t = 0; t < 16; ++t) {
            const f16x8 a0 = *reinterpret_cast<const f16x8*>(&A[am0][kfb + t * 16]);
            const f16x8 a1 = *reinterpret_cast<const f16x8*>(&A[am1][kfb + t * 16]);
            acc0 = __builtin_amdgcn_mfma_f32_32x32x16_f16(a0, bh[t], acc0, 0, 0, 0);
            acc1 = __builtin_amdgcn_mfma_f32_32x32x16_f16(a1, bh[t], acc1, 0, 0, 0);
        }
        __syncthreads();                          // A reads done -> Red alias safe

        // ---- k-quarter reduce: kq 1..3 write partials ----
        if (kq > 0) {
            const int base = ((nh * 3 + (kq - 1)) * 2) * 16 * 64;
#pragma unroll
            for (int r = 0; r < 16; ++r) {
                Red[base + r * 64 + lane]        = acc0[r];
                Red[base + (16 + r) * 64 + lane] = acc1[r];
            }
        }
        __syncthreads();

        // ---- kq==0: combine + tanh + L2-coherent H store + out store ----
        if (kq == 0) {
#pragma unroll
            for (int f = 0; f < 2; ++f) {
#pragma unroll
                for (int r = 0; r < 16; ++r) {
                    float v = f ? acc1[r] : acc0[r];
#pragma unroll
                    for (int q = 0; q < 3; ++q)
                        v += Red[(((nh * 3 + q) * 2 + f) * 16 + r) * 64 + lane];
                    const int srow = (r & 3) + 8 * (r >> 2) + 4 * (lane >> 5);
                    const int s = row0 + f * 32 + srow;
                    const int t = (s & 511) * CHUNK + (i - WU);
                    float h = 0.f;
                    if (t >= 0) h = tanhf(v + xpv[f][r]);
                    const half_t hh = (half_t)h;
                    st_l2(Hout + (size_t)s * DIM + col,
                          *reinterpret_cast<const unsigned short*>(&hh));
                    if (i >= WU) {
                        const int orow = (s >> 9) ? (SEQ + t) : t;
                        out[(size_t)orow * DIM + col] = h;
                    }
                }
            }
        }

        // ---- slab-local barrier: 16 co-XCD blocks, relaxed atomics ----
        if (i < NSTEP - 1) {
            asm volatile("s_waitcnt vmcnt(0)" ::: "memory");   // H stores at L2
            __syncthreads();
            if (tid == 0) {
                __hip_atomic_fetch_add(mybar, 1u,
                                       __ATOMIC_RELAXED, __HIP_MEMORY_SCOPE_AGENT);
                while (__hip_atomic_load(mybar, __ATOMIC_RELAXED,
                                         __HIP_MEMORY_SCOPE_AGENT) < 16u * (i + 1))
                    __builtin_amdgcn_s_sleep(1);
            }
            __syncthreads();
        }
    }
}

// ---------------------------------------------------------------------------
extern "C" void kernel_launch(void* const* d_in, const int* in_sizes, int n_in,
                              void* d_out, int out_size, void* d_ws, size_t ws_size,
                              hipStream_t stream)
{
    (void)in_sizes; (void)n_in; (void)out_size; (void)ws_size;
    const float* x  = (const float*)d_in[0];
    const float* Wx = (const float*)d_in[1];
    const float* Wh = (const float*)d_in[2];
    const float* b  = (const float*)d_in[3];
    float* out = (float*)d_out;

    char* ws = (char*)d_ws;
    const size_t MB = 1ull << 20;
    float*  xp  = (float*)ws;                        // [0, 64MB)
    half_t* WxT = (half_t*)(ws + 64 * MB);           // 2MB
    half_t* WhT = (half_t*)(ws + 66 * MB);           // 2MB
    half_t* H0  = (half_t*)(ws + 68 * MB);           // 2MB
    half_t* H1  = (half_t*)(ws + 70 * MB);           // 2MB
    unsigned int* bar = (unsigned int*)(ws + 72 * MB);  // 2KB counters

    half_t* xh = (half_t*)d_out;    // first 32MB of out; consumed by xproj
                                    // before steps overwrite out (stream order)

    hipLaunchKernelGGL(whalf_kernel, dim3(256), dim3(256), 0, stream, Wx, WxT);
    hipLaunchKernelGGL(whalf_kernel, dim3(256), dim3(256), 0, stream, Wh, WhT);
    hipLaunchKernelGGL(xhalf_kernel, dim3(1024), dim3(256), 0, stream, x, xh);
    hipLaunchKernelGGL(xproj_f16, dim3(2048), dim3(256), 0, stream,
                       xh, WxT, b, xp);
    hipMemsetAsync(H0, 0, 2 * MB, stream);
    hipMemsetAsync(bar, 0, 2048, stream);

    void* args[] = {(void*)&H0, (void*)&H1, (void*)&xp,
                    (void*)&WhT, (void*)&out, (void*)&bar};
    hipLaunchCooperativeKernel((void*)step_persist5, dim3(256), dim3(512),
                               args, 0, stream);
}

// Round 10
// 390.253 us; speedup vs baseline: 4.4358x; 1.8545x over previous
//
#include <hip/hip_runtime.h>
#include <math.h>

#define SEQ   16384
#define DIM   1024
#define WU    24                    // warm-up (empirical bound: chi<0.835 -> resid <0.009)
#define CHUNK 32
#define NCH   (SEQ / CHUNK)         // 512 chunks per direction
#define NSTR  (2 * NCH)             // 1024 parallel streams
#define NSTEP (WU + CHUNK)          // 56 batched steps

typedef _Float16 half_t;
typedef __attribute__((ext_vector_type(4)))  _Float16 f16x4;
typedef __attribute__((ext_vector_type(8)))  _Float16 f16x8;
typedef __attribute__((ext_vector_type(16))) float    f32x16;

// Intra-XCD coherent access: sc0 bypasses L1, served by the XCD-shared L2.
// memory clobber keeps asm VMEM ops ordered so partial vmcnt counts are exact.
__device__ __forceinline__ uint4 ld_l2(const void* p) {
    uint4 r;
    asm volatile("global_load_dwordx4 %0, %1, off sc0"
                 : "=v"(r) : "v"(p) : "memory");
    return r;
}
__device__ __forceinline__ void st_l2(void* p, unsigned short v) {
    asm volatile("global_store_short %0, %1, off sc0"
                 :: "v"(p), "v"((unsigned int)v) : "memory");
}

__device__ __forceinline__ float fast_tanh(float z) {
    // tanh(z) = (e^{2z}-1)/(e^{2z}+1), e^{2z} = exp2(z * 2/ln2)
    const float a = __builtin_amdgcn_exp2f(z * 2.885390081777927f);
    return (a - 1.f) * __builtin_amdgcn_rcpf(a + 1.f);
}

// ---------------------------------------------------------------------------
// W (KxN fp32) -> n-major NxK fp16.  Used for Wx and Wh.
// ---------------------------------------------------------------------------
__global__ __launch_bounds__(256)
void whalf_kernel(const float* __restrict__ W, half_t* __restrict__ WT)
{
    const int bk = blockIdx.x & 15, bn = blockIdx.x >> 4;
    const int k0 = bk * 64, n0 = bn * 64;
    const int tid = threadIdx.x;
    __shared__ float T[64][65];
#pragma unroll
    for (int it = 0; it < 4; ++it) {
        int f = tid + 256 * it;
        int r = f >> 4;
        int c4 = (f & 15) << 2;
        const float4 v = *reinterpret_cast<const float4*>(
            &W[(size_t)(k0 + r) * DIM + n0 + c4]);
        T[r][c4 + 0] = v.x; T[r][c4 + 1] = v.y;
        T[r][c4 + 2] = v.z; T[r][c4 + 3] = v.w;
    }
    __syncthreads();
#pragma unroll
    for (int it = 0; it < 4; ++it) {
        int f  = tid + 256 * it;
        int rn = f >> 4;
        int c4 = (f & 15) << 2;
        f16x4 o;
        o[0] = (half_t)T[c4 + 0][rn]; o[1] = (half_t)T[c4 + 1][rn];
        o[2] = (half_t)T[c4 + 2][rn]; o[3] = (half_t)T[c4 + 3][rn];
        *reinterpret_cast<f16x4*>(&WT[(size_t)(n0 + rn) * DIM + k0 + c4]) = o;
    }
}

// ---------------------------------------------------------------------------
// x (fp32) -> fp16, same layout. Memory-bound.
// ---------------------------------------------------------------------------
__global__ __launch_bounds__(256)
void xhalf_kernel(const float* __restrict__ x, half_t* __restrict__ xh)
{
    const int N8 = SEQ * DIM / 8;
    for (int idx = blockIdx.x * 256 + threadIdx.x; idx < N8; idx += gridDim.x * 256) {
        const float4 a = reinterpret_cast<const float4*>(x)[2 * idx];
        const float4 b = reinterpret_cast<const float4*>(x)[2 * idx + 1];
        f16x8 o;
        o[0] = (half_t)a.x; o[1] = (half_t)a.y; o[2] = (half_t)a.z; o[3] = (half_t)a.w;
        o[4] = (half_t)b.x; o[5] = (half_t)b.y; o[6] = (half_t)b.z; o[7] = (half_t)b.w;
        reinterpret_cast<f16x8*>(xh)[idx] = o;
    }
}

// ---------------------------------------------------------------------------
// xproj = x @ Wx + b, MFMA 32x32x16 fp16 single-term. (r8 version, proven)
// ---------------------------------------------------------------------------
__global__ __launch_bounds__(256)
void xproj_f16(const half_t* __restrict__ xh, const half_t* __restrict__ WxT,
               const float* __restrict__ b, float* __restrict__ xp)
{
    const int gb = (blockIdx.x & 7) * 256 + (blockIdx.x >> 3);
    const int bm = gb >> 4, bn = gb & 15;
    const int row0 = bm * 128, col0 = bn * 64;
    const int tid = threadIdx.x, lane = tid & 63, w = tid >> 6;
    const int wm = w >> 1, wn = w & 1;

    __shared__ half_t Ah[128][40], Bh[64][40];

    f32x16 acc[2];
#pragma unroll
    for (int mi = 0; mi < 2; ++mi)
#pragma unroll
        for (int r = 0; r < 16; ++r) acc[mi][r] = 0.f;

    const int ar = tid >> 1, ak = (tid & 1) * 16;   // A: 128r x 32k, 2 uint4/thr
    const int br = tid >> 2, bk2 = (tid & 3) * 8;   // B: 64r x 32k, 1 uint4/thr
    const size_t ga  = (size_t)(row0 + ar) * DIM + ak;
    const size_t gbb = (size_t)(col0 + br) * DIM + bk2;

    uint4 pa0, pa1, pb;
#define XLOAD(k0_) do {                                                        \
        pa0 = *reinterpret_cast<const uint4*>(xh + ga + (k0_));                \
        pa1 = *reinterpret_cast<const uint4*>(xh + ga + (k0_) + 8);            \
        pb  = *reinterpret_cast<const uint4*>(WxT + gbb + (k0_));              \
    } while (0)

    XLOAD(0);
    const int am0 = wm * 64 + (lane & 31), am1 = am0 + 32;
    const int bn0 = wn * 32 + (lane & 31);
    const int kh  = (lane >> 5) * 8;

    for (int kt = 0; kt < 32; ++kt) {
        __syncthreads();
        *reinterpret_cast<uint4*>(&Ah[ar][ak])     = pa0;
        *reinterpret_cast<uint4*>(&Ah[ar][ak + 8]) = pa1;
        *reinterpret_cast<uint4*>(&Bh[br][bk2])    = pb;
        __syncthreads();
        if (kt < 31) XLOAD((size_t)(kt + 1) * 32);
#pragma unroll
        for (int ks = 0; ks < 2; ++ks) {
            const int ko = ks * 16 + kh;
            f16x8 a0 = *reinterpret_cast<const f16x8*>(&Ah[am0][ko]);
            f16x8 a1 = *reinterpret_cast<const f16x8*>(&Ah[am1][ko]);
            f16x8 bb = *reinterpret_cast<const f16x8*>(&Bh[bn0][ko]);
            acc[0] = __builtin_amdgcn_mfma_f32_32x32x16_f16(a0, bb, acc[0], 0, 0, 0);
            acc[1] = __builtin_amdgcn_mfma_f32_32x32x16_f16(a1, bb, acc[1], 0, 0, 0);
        }
    }
#undef XLOAD

    // C layout (m74/m101): col = lane&31, row = (r&3) + 8*(r>>2) + 4*(lane>>5)
    const int rbase = 4 * (lane >> 5);
    const int col = col0 + wn * 32 + (lane & 31);
    const float bb = b[col];
#pragma unroll
    for (int mi = 0; mi < 2; ++mi) {
#pragma unroll
        for (int r = 0; r < 16; ++r) {
            const int row = row0 + wm * 64 + mi * 32 + (r & 3) + 8 * (r >> 2) + rbase;
            xp[(size_t)row * DIM + col] = acc[mi][r] + bb;
        }
    }
}

// ---------------------------------------------------------------------------
// Persistent step kernel v6 = r9's v5 (intra-XCD exchange, proven) with:
//   * epilogue spread over ALL 8 waves (r9: 2/8 waves -> serial tail):
//     all 4 kq waves write partials to Red[4][64][64]; each wave then owns
//     8 stream-rows x 64 cols -> coalesced 128B H / 256B out stores.
//   * staging partial drains: 16 asm loads, vmcnt(8), write, vmcnt(0), write.
//   * out stores issued AFTER barrier arrival (overlap the poll).
//   * fast exp2-based tanh.
//   * WU=24 -> 56 steps.
// ---------------------------------------------------------------------------
__global__ __launch_bounds__(512)
void step_persist6(half_t* __restrict__ Ha,
                   half_t* __restrict__ Hb,
                   const float* __restrict__ xp,
                   const half_t* __restrict__ WhT,
                   float* __restrict__ out,
                   unsigned int* bar)
{
    const int blk = blockIdx.x;
    const int slab = (blk & 7) * 2 + ((blk >> 3) & 1);   // co-XCD per slab
    const int panel = blk >> 4;                          // 0..15
    const int row0 = slab * 64, col0 = panel * 64;
    const int tid = threadIdx.x, lane = tid & 63, w = tid >> 6;
    const int nh = w & 1, kq = w >> 1;

    __shared__ half_t A[64][1036];                         // 129.5 KB
    float* Red = reinterpret_cast<float*>(&A[0][0]);       // 64KB alias [4][64][64]

    // ---- one-time: Wh panel fragment into registers (64 VGPR) ----
    f16x8 bh[16];
    {
        const size_t bbase = (size_t)(col0 + nh * 32 + (lane & 31)) * DIM
                           + kq * 256 + (lane >> 5) * 8;
#pragma unroll
        for (int t = 0; t < 16; ++t)
            bh[t] = *reinterpret_cast<const f16x8*>(&WhT[bbase + t * 16]);
    }

    const int strow = tid >> 3, stc = tid & 7;    // staging: 8 thr/row
    const size_t gH = (size_t)(row0 + strow) * DIM + stc * 8;
    const int am0 = lane & 31, am1 = 32 + (lane & 31);
    const int kfb = kq * 256 + (lane >> 5) * 8;
    unsigned int* mybar = bar + slab * 32;        // 128B-isolated counter

    for (int i = 0; i < NSTEP; ++i) {
        const half_t* Hin = (i & 1) ? Hb : Ha;
        half_t*      Hout = (i & 1) ? Ha : Hb;

        // ---- stage H slab: 16 ordered coherent loads, partial drains ----
        uint4 st[16];
#pragma unroll
        for (int q = 0; q < 16; ++q)
            st[q] = ld_l2(Hin + gH + (size_t)q * 64);
        asm volatile("s_waitcnt vmcnt(8)" ::: "memory");
        __builtin_amdgcn_sched_barrier(0);
#pragma unroll
        for (int q = 0; q < 8; ++q)
            *reinterpret_cast<uint4*>(&A[strow][(stc + 8 * q) * 8]) = st[q];
        asm volatile("s_waitcnt vmcnt(0)" ::: "memory");
        __builtin_amdgcn_sched_barrier(0);
#pragma unroll
        for (int q = 8; q < 16; ++q)
            *reinterpret_cast<uint4*>(&A[strow][(stc + 8 * q) * 8]) = st[q];

        // ---- xp prefetch: each wave owns 8 stream-rows, lane = col ----
        float xpv[8];
#pragma unroll
        for (int rr = 0; rr < 8; ++rr) {
            const int s = row0 + 8 * w + rr;
            const int t = (s & 511) * CHUNK + (i - WU);
            const int xrow = (t < 0) ? 0 : ((s >> 9) ? (SEQ - 1 - t) : t);
            xpv[rr] = xp[(size_t)xrow * DIM + col0 + lane];
        }
        __syncthreads();

        // ---- MFMA over this wave's k-quarter, B from registers ----
        f32x16 acc0, acc1;
#pragma unroll
        for (int r = 0; r < 16; ++r) { acc0[r] = 0.f; acc1[r] = 0.f; }
#pragma unroll
        for (int t = 0; t < 16; ++t) {
            const f16x8 a0 = *reinterpret_cast<const f16x8*>(&A[am0][kfb + t * 16]);
            const f16x8 a1 = *reinterpret_cast<const f16x8*>(&A[am1][kfb + t * 16]);
            acc0 = __builtin_amdgcn_mfma_f32_32x32x16_f16(a0, bh[t], acc0, 0, 0, 0);
            acc1 = __builtin_amdgcn_mfma_f32_32x32x16_f16(a1, bh[t], acc1, 0, 0, 0);
        }
        __syncthreads();                          // A reads done -> Red alias safe

        // ---- all 4 kq waves write partials: Red[kq][srow][col] ----
        {
            const int base = kq * 4096 + nh * 32 + (lane & 31);
#pragma unroll
            for (int r = 0; r < 16; ++r) {
                const int srow = (r & 3) + 8 * (r >> 2) + 4 * (lane >> 5);
                Red[base + srow * 64]        = acc0[r];
                Red[base + (srow + 32) * 64] = acc1[r];
            }
        }
        __syncthreads();

        // ---- combine spread over all 8 waves: 8 rows x 64 cols each ----
        float valr[8];
#pragma unroll
        for (int rr = 0; rr < 8; ++rr) {
            const int sl = 8 * w + rr;
            const int idx = sl * 64 + lane;
            const float v = Red[idx] + Red[4096 + idx]
                          + Red[8192 + idx] + Red[12288 + idx];
            const int s = row0 + sl;
            const int t = (s & 511) * CHUNK + (i - WU);
            const float h = (t >= 0) ? fast_tanh(v + xpv[rr]) : 0.f;
            valr[rr] = h;
            const half_t hh = (half_t)h;
            st_l2(Hout + (size_t)s * DIM + col0 + lane,
                  *reinterpret_cast<const unsigned short*>(&hh));
        }

        // ---- barrier arrival, then out stores overlap the poll ----
        asm volatile("s_waitcnt vmcnt(0)" ::: "memory");   // H stores at L2
        __syncthreads();
        if (i < NSTEP - 1 && tid == 0)
            __hip_atomic_fetch_add(mybar, 1u,
                                   __ATOMIC_RELAXED, __HIP_MEMORY_SCOPE_AGENT);
        if (i >= WU) {
#pragma unroll
            for (int rr = 0; rr < 8; ++rr) {
                const int s = row0 + 8 * w + rr;
                const int t = (s & 511) * CHUNK + (i - WU);
                const int orow = (s >> 9) ? (SEQ + t) : t;
                out[(size_t)orow * DIM + col0 + lane] = valr[rr];
            }
        }
        if (i < NSTEP - 1) {
            if (tid == 0) {
                while (__hip_atomic_load(mybar, __ATOMIC_RELAXED,
                                         __HIP_MEMORY_SCOPE_AGENT) < 16u * (i + 1))
                    __builtin_amdgcn_s_sleep(1);
            }
            __syncthreads();
        }
    }
}

// ---------------------------------------------------------------------------
extern "C" void kernel_launch(void* const* d_in, const int* in_sizes, int n_in,
                              void* d_out, int out_size, void* d_ws, size_t ws_size,
                              hipStream_t stream)
{
    (void)in_sizes; (void)n_in; (void)out_size; (void)ws_size;
    const float* x  = (const float*)d_in[0];
    const float* Wx = (const float*)d_in[1];
    const float* Wh = (const float*)d_in[2];
    const float* b  = (const float*)d_in[3];
    float* out = (float*)d_out;

    char* ws = (char*)d_ws;
    const size_t MB = 1ull << 20;
    float*  xp  = (float*)ws;                        // [0, 64MB)
    half_t* WxT = (half_t*)(ws + 64 * MB);           // 2MB
    half_t* WhT = (half_t*)(ws + 66 * MB);           // 2MB
    half_t* H0  = (half_t*)(ws + 68 * MB);           // 2MB
    half_t* H1  = (half_t*)(ws + 70 * MB);           // 2MB
    unsigned int* bar = (unsigned int*)(ws + 72 * MB);  // 2KB counters

    half_t* xh = (half_t*)d_out;    // first 32MB of out; consumed by xproj
                                    // before steps overwrite out (stream order)

    hipLaunchKernelGGL(whalf_kernel, dim3(256), dim3(256), 0, stream, Wx, WxT);
    hipLaunchKernelGGL(whalf_kernel, dim3(256), dim3(256), 0, stream, Wh, WhT);
    hipLaunchKernelGGL(xhalf_kernel, dim3(1024), dim3(256), 0, stream, x, xh);
    hipLaunchKernelGGL(xproj_f16, dim3(2048), dim3(256), 0, stream,
                       xh, WxT, b, xp);
    hipMemsetAsync(H0, 0, 2 * MB, stream);
    hipMemsetAsync(bar, 0, 2048, stream);

    void* args[] = {(void*)&H0, (void*)&H1, (void*)&xp,
                    (void*)&WhT, (void*)&out, (void*)&bar};
    hipLaunchCooperativeKernel((void*)step_persist6, dim3(256), dim3(512),
                               args, 0, stream);
}